// Round 1
// baseline (745.901 us; speedup 1.0000x reference)
//
#include <hip/hip_runtime.h>

#define BB 8
#define CC 64
#define HH 96
#define WW 96
#define OO 64
#define KK 3
#define K2 9
#define HW (HH*WW)      // 9216
#define NOFF 18         // 2*K*K offset channels
#define NPIX (BB*HW)    // 73728

// ---------------- Kernel 1: offset conv (3x3, pad 1, stride 1) ----------------
__global__ __launch_bounds__(256) void offset_conv_kernel(
    const float* __restrict__ x, const float* __restrict__ w_off,
    const float* __restrict__ b_off, float* __restrict__ offset) {
  __shared__ float wl[NOFF * CC * K2];   // 10368 floats = 41.5 KB
  for (int i = threadIdx.x; i < NOFF * CC * K2; i += 256) wl[i] = w_off[i];
  __syncthreads();

  int idx = blockIdx.x * 256 + threadIdx.x;   // pixel over B*H*W
  int b  = idx / HW;
  int hw = idx % HW;
  int h = hw / WW, w = hw % WW;

  float acc[NOFF];
  #pragma unroll
  for (int j = 0; j < NOFF; ++j) acc[j] = b_off[j];

  const float* xb = x + (size_t)b * CC * HW;
  for (int ky = 0; ky < KK; ++ky) {
    int y = h - 1 + ky;
    if ((unsigned)y >= HH) continue;
    for (int kx = 0; kx < KK; ++kx) {
      int xx = w - 1 + kx;
      if ((unsigned)xx >= WW) continue;
      int kt = ky * KK + kx;
      const float* xp = xb + y * WW + xx;
      #pragma unroll 4
      for (int c = 0; c < CC; ++c) {
        float xv = xp[c * HW];
        #pragma unroll
        for (int j = 0; j < NOFF; ++j)
          acc[j] = fmaf(xv, wl[(j * CC + c) * K2 + kt], acc[j]);
      }
    }
  }
  float* op = offset + (size_t)b * NOFF * HW + hw;
  #pragma unroll
  for (int j = 0; j < NOFF; ++j) op[j * HW] = acc[j];
}

// ---------------- Kernel 2: deformable conv ----------------
// one thread = one output pixel (b,h,w); 64 fp32 accumulators (all out chans)
__global__ __launch_bounds__(256) void dcn_kernel(
    const float* __restrict__ x, const float* __restrict__ offset,
    const float* __restrict__ w_dcn, float* __restrict__ out) {
  __shared__ float wk[CC * OO];   // 16 KB per-k weight tile, layout [c][o]

  int idx = blockIdx.x * 256 + threadIdx.x;
  int b  = idx / HW;
  int hw = idx % HW;
  int h = hw / WW, w = hw % WW;

  float acc[OO];
  #pragma unroll
  for (int o = 0; o < OO; ++o) acc[o] = 0.f;

  const float* xb   = x + (size_t)b * CC * HW;
  const float* offp = offset + (size_t)b * NOFF * HW + hw;

  for (int k = 0; k < K2; ++k) {
    __syncthreads();
    // stage w_dcn[o][c][k] -> wk[c*OO + o]
    for (int i = threadIdx.x; i < CC * OO; i += 256) {
      int c = i / OO, o = i % OO;
      wk[i] = w_dcn[(o * CC + c) * K2 + k];
    }
    __syncthreads();

    int ky = k / KK, kx = k % KK;
    float dy = offp[(2 * k) * HW];
    float dx = offp[(2 * k + 1) * HW];
    float py = dy + (float)(h - 1 + ky);
    float px = dx + (float)(w - 1 + kx);

    float y0f = floorf(py), x0f = floorf(px);
    float wy = py - y0f, wx = px - x0f;
    int y0 = (int)y0f, x0 = (int)x0f;
    int y1 = y0 + 1, x1 = x0 + 1;

    bool vy0 = (unsigned)y0 < HH, vy1 = (unsigned)y1 < HH;
    bool vx0 = (unsigned)x0 < WW, vx1 = (unsigned)x1 < WW;
    int cy0 = min(max(y0, 0), HH - 1), cy1 = min(max(y1, 0), HH - 1);
    int cx0 = min(max(x0, 0), WW - 1), cx1 = min(max(x1, 0), WW - 1);

    float w00 = (1.f - wy) * (1.f - wx) * ((vy0 && vx0) ? 1.f : 0.f);
    float w01 = (1.f - wy) * wx         * ((vy0 && vx1) ? 1.f : 0.f);
    float w10 = wy * (1.f - wx)         * ((vy1 && vx0) ? 1.f : 0.f);
    float w11 = wy * wx                 * ((vy1 && vx1) ? 1.f : 0.f);

    int i00 = cy0 * WW + cx0, i01 = cy0 * WW + cx1;
    int i10 = cy1 * WW + cx0, i11 = cy1 * WW + cx1;

    #pragma unroll 2
    for (int c = 0; c < CC; ++c) {
      const float* xc = xb + c * HW;
      float s = w00 * xc[i00] + w01 * xc[i01] + w10 * xc[i10] + w11 * xc[i11];
      const float* wrow = &wk[c * OO];
      #pragma unroll
      for (int o = 0; o < OO; ++o)
        acc[o] = fmaf(s, wrow[o], acc[o]);
    }
  }

  float* op = out + (size_t)b * OO * HW + hw;
  #pragma unroll
  for (int o = 0; o < OO; ++o) op[o * HW] = acc[o];
}

extern "C" void kernel_launch(void* const* d_in, const int* in_sizes, int n_in,
                              void* d_out, int out_size, void* d_ws, size_t ws_size,
                              hipStream_t stream) {
  const float* x     = (const float*)d_in[0];
  const float* w_off = (const float*)d_in[1];
  const float* b_off = (const float*)d_in[2];
  const float* w_dcn = (const float*)d_in[3];
  float* out = (float*)d_out;
  float* offset = (float*)d_ws;   // [B, 18, 96, 96] fp32 = 5.3 MB scratch

  offset_conv_kernel<<<NPIX / 256, 256, 0, stream>>>(x, w_off, b_off, offset);
  dcn_kernel<<<NPIX / 256, 256, 0, stream>>>(x, offset, w_dcn, out);
}

// Round 3
// 247.158 us; speedup vs baseline: 3.0179x; 3.0179x over previous
//
#include <hip/hip_runtime.h>

#define BB 8
#define CC 64
#define HH 96
#define WW 96
#define OO 64
#define KK 3
#define K2 9
#define HW (HH*WW)      // 9216
#define NOFF 18
#define NPIX (BB*HW)    // 73728
#define MT 64           // pixels per dcn block
#define NTILE (HW/MT)   // 144 tiles per image
#define ROWB 144        // LDS row stride bytes (9*16)

typedef __attribute__((ext_vector_type(8))) short   short8v;
typedef __attribute__((ext_vector_type(8))) unsigned short ushort8v;
typedef __attribute__((ext_vector_type(4))) float   f32x4;
typedef __attribute__((ext_vector_type(4))) unsigned int uint4v;

__device__ __forceinline__ unsigned short f2bf(float f) {
  unsigned u = __float_as_uint(f);
  u += 0x7fffu + ((u >> 16) & 1u);        // RTNE
  return (unsigned short)(u >> 16);
}
__device__ __forceinline__ float bf2f(unsigned short b) {
  return __uint_as_float(((unsigned)b) << 16);
}

// ---------------- Kernel T: NCHW fp32 -> NHWC bf16 ----------------
__global__ __launch_bounds__(256) void transpose_kernel(
    const float* __restrict__ x, unsigned short* __restrict__ xt) {
  int idx = blockIdx.x * 256 + threadIdx.x;   // pixel over B*HW
  int b = idx / HW, hw = idx % HW;
  const float* xp = x + (size_t)b * CC * HW + hw;
  unsigned short r[CC];
  #pragma unroll
  for (int c = 0; c < CC; ++c) r[c] = f2bf(xp[c * HW]);   // coalesced across lanes
  uint4v* dst = (uint4v*)(xt + (size_t)idx * CC);
  #pragma unroll
  for (int j = 0; j < 8; ++j) {
    uint4v v;
    #pragma unroll
    for (int q = 0; q < 4; ++q)
      v[q] = (unsigned)r[j*8 + q*2] | ((unsigned)r[j*8 + q*2 + 1] << 16);
    dst[j] = v;
  }
}

// ---------------- Kernel W: w_dcn [O][C][K2] fp32 -> wt [K2][O][C] bf16 -----
__global__ __launch_bounds__(256) void wconv_kernel(
    const float* __restrict__ w_dcn, unsigned short* __restrict__ wt) {
  int idx = blockIdx.x * 256 + threadIdx.x;   // K2*OO*CC = 36864
  int k = idx / (OO * CC);
  int o = (idx / CC) % OO;
  int c = idx % CC;
  wt[idx] = f2bf(w_dcn[(o * CC + c) * K2 + k]);
}

// ---------------- Kernel 1: offset conv (unchanged, known-good) -------------
__global__ __launch_bounds__(256) void offset_conv_kernel(
    const float* __restrict__ x, const float* __restrict__ w_off,
    const float* __restrict__ b_off, float* __restrict__ offset) {
  __shared__ float wl[NOFF * CC * K2];
  for (int i = threadIdx.x; i < NOFF * CC * K2; i += 256) wl[i] = w_off[i];
  __syncthreads();

  int idx = blockIdx.x * 256 + threadIdx.x;
  int b  = idx / HW;
  int hw = idx % HW;
  int h = hw / WW, w = hw % WW;

  float acc[NOFF];
  #pragma unroll
  for (int j = 0; j < NOFF; ++j) acc[j] = b_off[j];

  const float* xb = x + (size_t)b * CC * HW;
  for (int ky = 0; ky < KK; ++ky) {
    int y = h - 1 + ky;
    if ((unsigned)y >= HH) continue;
    for (int kx = 0; kx < KK; ++kx) {
      int xx = w - 1 + kx;
      if ((unsigned)xx >= WW) continue;
      int kt = ky * KK + kx;
      const float* xp = xb + y * WW + xx;
      #pragma unroll 4
      for (int c = 0; c < CC; ++c) {
        float xv = xp[c * HW];
        #pragma unroll
        for (int j = 0; j < NOFF; ++j)
          acc[j] = fmaf(xv, wl[(j * CC + c) * K2 + kt], acc[j]);
      }
    }
  }
  float* op = offset + (size_t)b * NOFF * HW + hw;
  #pragma unroll
  for (int j = 0; j < NOFF; ++j) op[j * HW] = acc[j];
}

// ---------------- Kernel 2: deformable conv — fp32 FMA from bf16 tiles ------
// BISECT ROUND: staging identical to the MFMA version (same xt/wt/phase-0/
// bilinear/f2bf path), but the contraction is plain fp32 FMA. If this passes,
// the staged data is verified and the R2 bug is MFMA-local.
__global__ __launch_bounds__(256) void dcn_fma_kernel(
    const unsigned short* __restrict__ xt,   // [B][HW][C] bf16
    const float* __restrict__ offset,        // [B][18][HW] fp32
    const unsigned short* __restrict__ wt,   // [K2][O][C] bf16
    float* __restrict__ out) {
  __shared__ int   pidx[576 * 4];
  __shared__ float pwt [576 * 4];
  __shared__ char  Albs[64 * ROWB];   // [m][g=0..7][16B], row stride 144 B
  __shared__ char  Blbs[64 * ROWB];   // [o][g][16B]

  int t = threadIdx.x;
  int blk = blockIdx.x;
  int b = blk / NTILE;
  int hw0 = (blk % NTILE) * MT;

  const char*  xb   = (const char*)(xt + (size_t)b * HW * CC);  // 128 B / pixel
  const float* offb = offset + (size_t)b * NOFF * HW + hw0;

  // ---- phase 0: bilinear params for 64 pixels x 9 taps (verbatim from R2) ----
  for (int p = t; p < 576; p += 256) {
    int k = p >> 6, m = p & 63;
    int hw = hw0 + m;
    int h = hw / WW, w = hw % WW;
    int ky = k / KK, kx = k % KK;
    float py = offb[(2 * k) * HW + m]     + (float)(h - 1 + ky);
    float px = offb[(2 * k + 1) * HW + m] + (float)(w - 1 + kx);
    float y0f = floorf(py), x0f = floorf(px);
    float wy = py - y0f, wx = px - x0f;
    int y0 = (int)y0f, x0 = (int)x0f;
    int y1 = y0 + 1, x1 = x0 + 1;
    bool vy0 = (unsigned)y0 < HH, vy1 = (unsigned)y1 < HH;
    bool vx0 = (unsigned)x0 < WW, vx1 = (unsigned)x1 < WW;
    int cy0 = min(max(y0, 0), HH - 1), cy1 = min(max(y1, 0), HH - 1);
    int cx0 = min(max(x0, 0), WW - 1), cx1 = min(max(x1, 0), WW - 1);
    pwt[p * 4 + 0] = (1.f - wy) * (1.f - wx) * ((vy0 && vx0) ? 1.f : 0.f);
    pwt[p * 4 + 1] = (1.f - wy) * wx         * ((vy0 && vx1) ? 1.f : 0.f);
    pwt[p * 4 + 2] = wy * (1.f - wx)         * ((vy1 && vx0) ? 1.f : 0.f);
    pwt[p * 4 + 3] = wy * wx                 * ((vy1 && vx1) ? 1.f : 0.f);
    pidx[p * 4 + 0] = (cy0 * WW + cx0) * (CC * 2);
    pidx[p * 4 + 1] = (cy0 * WW + cx1) * (CC * 2);
    pidx[p * 4 + 2] = (cy1 * WW + cx0) * (CC * 2);
    pidx[p * 4 + 3] = (cy1 * WW + cx1) * (CC * 2);
  }
  __syncthreads();

  // staging thread mapping (same as R2): pixel/o = sm, 16-ch block cb
  int sm = (t & 15) + (t >> 6) * 16;
  int cb = (t >> 4) & 3;

  // compute thread mapping: 4 pixels x 4 out-channels per thread
  int mg = t >> 4;   // 0..15 -> pixels mg*4..mg*4+3
  int og = t & 15;   // 0..15 -> outs   og*4..og*4+3

  float acc[4][4];
  #pragma unroll
  for (int p = 0; p < 4; ++p)
    #pragma unroll
    for (int q = 0; q < 4; ++q) acc[p][q] = 0.f;

  for (int k = 0; k < K2; ++k) {
    // ---- stage B: wt[k][o][c] -> Blbs[o][g][16B] ----
    {
      const uint4v* wk = (const uint4v*)(wt + (size_t)k * OO * CC + sm * CC + cb * 16);
      uint4v wb0 = wk[0];
      uint4v wb1 = wk[1];
      *(uint4v*)&Blbs[sm * ROWB + (cb * 2 + 0) * 16] = wb0;
      *(uint4v*)&Blbs[sm * ROWB + (cb * 2 + 1) * 16] = wb1;
    }
    // ---- stage A: bilinear sample 16 channels for pixel sm (verbatim math) --
    {
      int pb = (k * 64 + sm) * 4;
      int i0 = pidx[pb + 0], i1 = pidx[pb + 1], i2 = pidx[pb + 2], i3 = pidx[pb + 3];
      float w0 = pwt[pb + 0], w1 = pwt[pb + 1], w2 = pwt[pb + 2], w3 = pwt[pb + 3];
      int co = cb * 32;
      ushort8v v0a = *(const ushort8v*)(xb + i0 + co);
      ushort8v v0b = *(const ushort8v*)(xb + i0 + co + 16);
      ushort8v v1a = *(const ushort8v*)(xb + i1 + co);
      ushort8v v1b = *(const ushort8v*)(xb + i1 + co + 16);
      ushort8v v2a = *(const ushort8v*)(xb + i2 + co);
      ushort8v v2b = *(const ushort8v*)(xb + i2 + co + 16);
      ushort8v v3a = *(const ushort8v*)(xb + i3 + co);
      ushort8v v3b = *(const ushort8v*)(xb + i3 + co + 16);
      uint4v pa, pb2;
      #pragma unroll
      for (int q = 0; q < 4; ++q) {
        float s0 = w0 * bf2f(v0a[q*2])   + w1 * bf2f(v1a[q*2])
                 + w2 * bf2f(v2a[q*2])   + w3 * bf2f(v3a[q*2]);
        float s1 = w0 * bf2f(v0a[q*2+1]) + w1 * bf2f(v1a[q*2+1])
                 + w2 * bf2f(v2a[q*2+1]) + w3 * bf2f(v3a[q*2+1]);
        pa[q] = (unsigned)f2bf(s0) | ((unsigned)f2bf(s1) << 16);
        float s2 = w0 * bf2f(v0b[q*2])   + w1 * bf2f(v1b[q*2])
                 + w2 * bf2f(v2b[q*2])   + w3 * bf2f(v3b[q*2]);
        float s3 = w0 * bf2f(v0b[q*2+1]) + w1 * bf2f(v1b[q*2+1])
                 + w2 * bf2f(v2b[q*2+1]) + w3 * bf2f(v3b[q*2+1]);
        pb2[q] = (unsigned)f2bf(s2) | ((unsigned)f2bf(s3) << 16);
      }
      *(uint4v*)&Albs[sm * ROWB + (cb * 2 + 0) * 16] = pa;
      *(uint4v*)&Albs[sm * ROWB + (cb * 2 + 1) * 16] = pb2;
    }
    __syncthreads();

    // ---- fp32 FMA contraction over this tap's 64 channels ----
    #pragma unroll
    for (int g = 0; g < 8; ++g) {
      float av[4][8], bv[4][8];
      #pragma unroll
      for (int p = 0; p < 4; ++p) {
        ushort8v va = *(const ushort8v*)&Albs[(mg * 4 + p) * ROWB + g * 16];
        #pragma unroll
        for (int e = 0; e < 8; ++e) av[p][e] = bf2f(va[e]);
      }
      #pragma unroll
      for (int q = 0; q < 4; ++q) {
        ushort8v vb = *(const ushort8v*)&Blbs[(og * 4 + q) * ROWB + g * 16];
        #pragma unroll
        for (int e = 0; e < 8; ++e) bv[q][e] = bf2f(vb[e]);
      }
      #pragma unroll
      for (int p = 0; p < 4; ++p)
        #pragma unroll
        for (int q = 0; q < 4; ++q)
          #pragma unroll
          for (int e = 0; e < 8; ++e)
            acc[p][q] = fmaf(av[p][e], bv[q][e], acc[p][q]);
    }
    __syncthreads();
  }

  // ---- epilogue: out[b][o][hw0 + m] ----
  float* ob = out + (size_t)b * OO * HW;
  #pragma unroll
  for (int q = 0; q < 4; ++q) {
    f32x4 v;
    v[0] = acc[0][q]; v[1] = acc[1][q]; v[2] = acc[2][q]; v[3] = acc[3][q];
    *(f32x4*)(ob + (size_t)(og * 4 + q) * HW + hw0 + mg * 4) = v;
  }
}

extern "C" void kernel_launch(void* const* d_in, const int* in_sizes, int n_in,
                              void* d_out, int out_size, void* d_ws, size_t ws_size,
                              hipStream_t stream) {
  const float* x     = (const float*)d_in[0];
  const float* w_off = (const float*)d_in[1];
  const float* b_off = (const float*)d_in[2];
  const float* w_dcn = (const float*)d_in[3];
  float* out = (float*)d_out;

  // workspace layout (same as R2 — also re-tests ws-size adequacy)
  char* ws = (char*)d_ws;
  float* offset = (float*)ws;                                      // 5,308,416 B
  unsigned short* xtp = (unsigned short*)(ws + 5308416);           // 9,437,184 B
  unsigned short* wtp = (unsigned short*)(ws + 5308416 + 9437184); //    73,728 B

  transpose_kernel<<<NPIX / 256, 256, 0, stream>>>(x, xtp);
  wconv_kernel<<<(K2 * OO * CC) / 256, 256, 0, stream>>>(w_dcn, wtp);
  offset_conv_kernel<<<NPIX / 256, 256, 0, stream>>>(x, w_off, b_off, offset);
  dcn_fma_kernel<<<BB * NTILE, 256, 0, stream>>>(xtp, offset, wtp, out);
}

// Round 4
// 121.154 us; speedup vs baseline: 6.1566x; 2.0400x over previous
//
#include <hip/hip_runtime.h>

#define BB 8
#define CC 64
#define HH 96
#define WW 96
#define OO 64
#define KK 3
#define K2 9
#define HW (HH*WW)      // 9216
#define NOFF 18
#define NPIX (BB*HW)    // 73728
#define MT 64           // pixels per dcn block
#define NTILE (HW/MT)   // 144 tiles per image

typedef _Float16 f16;
typedef __attribute__((ext_vector_type(2))) _Float16 f16x2;
typedef __attribute__((ext_vector_type(4))) float f32x4;
typedef __attribute__((ext_vector_type(4))) unsigned int uint4v;

#if __has_builtin(__builtin_amdgcn_fdot2)
__device__ __forceinline__ float dot2u(unsigned a, unsigned b, float c) {
  return __builtin_amdgcn_fdot2(__builtin_bit_cast(f16x2, a),
                                __builtin_bit_cast(f16x2, b), c, false);
}
#else
__device__ __forceinline__ float dot2u(unsigned a, unsigned b, float c) {
  f16x2 ha = __builtin_bit_cast(f16x2, a), hb = __builtin_bit_cast(f16x2, b);
  return c + (float)ha[0] * (float)hb[0] + (float)ha[1] * (float)hb[1];
}
#endif

__device__ __forceinline__ f16x2 bch(unsigned u) {
  return __builtin_bit_cast(f16x2, u);
}
__device__ __forceinline__ unsigned bcu(f16x2 h) {
  return __builtin_bit_cast(unsigned, h);
}

// LDS slot swizzle: row stride 128 B = 8 slots of 16 B.
__device__ __forceinline__ int swz(int row, int g) {
  return g ^ (((row >> 2) ^ ((row & 3) << 1)) & 7);
}

// ---------------- Kernel T: NCHW fp32 -> NHWC f16 ----------------
__global__ __launch_bounds__(256) void transpose_kernel(
    const float* __restrict__ x, unsigned short* __restrict__ xt) {
  int idx = blockIdx.x * 256 + threadIdx.x;   // pixel over B*HW
  int b = idx / HW, hw = idx % HW;
  const float* xp = x + (size_t)b * CC * HW + hw;
  f16 r[CC];
  #pragma unroll
  for (int c = 0; c < CC; ++c) r[c] = (f16)xp[c * HW];   // coalesced across lanes
  uint4v* dst = (uint4v*)(xt + (size_t)idx * CC);
  #pragma unroll
  for (int j = 0; j < 8; ++j) {
    uint4v v;
    #pragma unroll
    for (int q = 0; q < 4; ++q) {
      f16x2 p2 = {r[j*8 + q*2], r[j*8 + q*2 + 1]};
      v[q] = bcu(p2);
    }
    dst[j] = v;
  }
}

// ---------------- Kernel W: w_dcn [O][C][K2] fp32 -> wt [K2][O][C] f16 ------
__global__ void wprep_kernel(const float* __restrict__ w_dcn,
                             unsigned short* __restrict__ wt) {
  int idx = blockIdx.x * 256 + threadIdx.x;   // 36864
  int k = idx / (OO * CC);
  int o = (idx / CC) % OO;
  int c = idx % CC;
  f16 h = (f16)w_dcn[(o * CC + c) * K2 + k];
  wt[idx] = __builtin_bit_cast(unsigned short, h);
}

// ---------------- Kernel O: offset conv via dot2 ----------------
// block: 64 pixels x 4-way j-split = 256 threads; grid 1152
#define JW 72   // padded j-row stride in f16 (144 B -> bank offset 4 per j)
__global__ __launch_bounds__(256) void offconv_kernel(
    const unsigned short* __restrict__ xt, const float* __restrict__ w_off,
    const float* __restrict__ b_off, float* __restrict__ offset) {
  __shared__ unsigned short wl[K2 * NOFF * JW];   // 23328 B, f16 bits
  int t = threadIdx.x;
  for (int i = t; i < K2 * NOFF * CC; i += 256) {
    int kt = i / (NOFF * CC);
    int r = i - kt * (NOFF * CC);
    int j = r >> 6, c = r & 63;
    f16 h = (f16)w_off[(j * CC + c) * K2 + kt];
    wl[(kt * NOFF + j) * JW + c] = __builtin_bit_cast(unsigned short, h);
  }
  __syncthreads();

  int px = blockIdx.x * 64 + (t >> 2);
  int jg = t & 3;
  int b = px / HW, hw = px % HW;
  int h = hw / WW, w = hw % WW;
  int nj = (jg < 2) ? 5 : 4;

  float acc[5];
  #pragma unroll
  for (int i = 0; i < 5; ++i) acc[i] = (i < nj) ? b_off[jg + i * 4] : 0.f;

  const uint4v* xtb = (const uint4v*)(xt + (size_t)b * HW * CC);  // 8 uint4v/row
  for (int ky = 0; ky < KK; ++ky) {
    int y = h - 1 + ky;
    if ((unsigned)y >= HH) continue;
    for (int kx = 0; kx < KK; ++kx) {
      int xx = w - 1 + kx;
      if ((unsigned)xx >= WW) continue;
      int kt = ky * KK + kx;
      const uint4v* xr = xtb + (size_t)(y * WW + xx) * 8;
      uint4v xa[8];
      #pragma unroll
      for (int r = 0; r < 8; ++r) xa[r] = xr[r];
      for (int ji = 0; ji < nj; ++ji) {
        int j = jg + ji * 4;
        const uint4v* wr_ = (const uint4v*)&wl[(kt * NOFF + j) * JW];
        float a = acc[ji];
        #pragma unroll
        for (int r = 0; r < 8; ++r) {
          uint4v wv = wr_[r];
          uint4v xv = xa[r];
          a = dot2u(xv[0], wv[0], a);
          a = dot2u(xv[1], wv[1], a);
          a = dot2u(xv[2], wv[2], a);
          a = dot2u(xv[3], wv[3], a);
        }
        acc[ji] = a;
      }
    }
  }
  float* op = offset + (size_t)b * NOFF * HW + hw;
  for (int ji = 0; ji < nj; ++ji) op[(jg + ji * 4) * HW] = acc[ji];
}

// ---------------- Kernel D: deformable conv via dot2 ----------------
// block = 64 pixels, 256 threads; per thread 4 px x 4 outs
__global__ __launch_bounds__(256) void dcn_kernel(
    const unsigned short* __restrict__ xt,   // [B][HW][C] f16
    const float* __restrict__ offset,        // [B][18][HW] fp32
    const unsigned short* __restrict__ wt,   // [K2][O][C] f16
    float* __restrict__ out) {
  __shared__ unsigned short pidx[576 * 4];   // 4608 B (packed lin pixel idx)
  __shared__ float pwt [576 * 4];            // 9216 B
  __shared__ char Al[64 * 128];              // 8192 B, [row][slot swz]
  __shared__ char Bl[64 * 128];              // 8192 B

  int t = threadIdx.x;
  int blk = blockIdx.x;
  int b = blk / NTILE;
  int hw0 = (blk % NTILE) * MT;

  const char*  xb   = (const char*)(xt + (size_t)b * HW * CC);  // 128 B / pixel
  const float* offb = offset + (size_t)b * NOFF * HW + hw0;

  // ---- phase 0: bilinear params (verified R3 math; pidx now packed u16) ----
  for (int p = t; p < 576; p += 256) {
    int k = p >> 6, m = p & 63;
    int hw = hw0 + m;
    int h = hw / WW, w = hw % WW;
    int ky = k / KK, kx = k % KK;
    float py = offb[(2 * k) * HW + m]     + (float)(h - 1 + ky);
    float px = offb[(2 * k + 1) * HW + m] + (float)(w - 1 + kx);
    float y0f = floorf(py), x0f = floorf(px);
    float wy = py - y0f, wx = px - x0f;
    int y0 = (int)y0f, x0 = (int)x0f;
    int y1 = y0 + 1, x1 = x0 + 1;
    bool vy0 = (unsigned)y0 < HH, vy1 = (unsigned)y1 < HH;
    bool vx0 = (unsigned)x0 < WW, vx1 = (unsigned)x1 < WW;
    int cy0 = min(max(y0, 0), HH - 1), cy1 = min(max(y1, 0), HH - 1);
    int cx0 = min(max(x0, 0), WW - 1), cx1 = min(max(x1, 0), WW - 1);
    pwt[p * 4 + 0] = (1.f - wy) * (1.f - wx) * ((vy0 && vx0) ? 1.f : 0.f);
    pwt[p * 4 + 1] = (1.f - wy) * wx         * ((vy0 && vx1) ? 1.f : 0.f);
    pwt[p * 4 + 2] = wy * (1.f - wx)         * ((vy1 && vx0) ? 1.f : 0.f);
    pwt[p * 4 + 3] = wy * wx                 * ((vy1 && vx1) ? 1.f : 0.f);
    pidx[p * 4 + 0] = (unsigned short)(cy0 * WW + cx0);
    pidx[p * 4 + 1] = (unsigned short)(cy0 * WW + cx1);
    pidx[p * 4 + 2] = (unsigned short)(cy1 * WW + cx0);
    pidx[p * 4 + 3] = (unsigned short)(cy1 * WW + cx1);
  }
  __syncthreads();

  // staging mapping: pixel/out-chan = sm, 16-channel block cb
  int sm = (t & 15) + (t >> 6) * 16;
  int cb = (t >> 4) & 3;
  // compute mapping: 4 pixels x 4 outs per thread
  int mg = t >> 4;   // pixels mg*4 .. +3
  int og = t & 15;   // outs   og*4 .. +3

  float acc[4][4];
  #pragma unroll
  for (int p = 0; p < 4; ++p)
    #pragma unroll
    for (int q = 0; q < 4; ++q) acc[p][q] = 0.f;

  for (int k = 0; k < K2; ++k) {
    int fs = ((sm >> 2) ^ ((sm & 3) << 1)) & 7;
    // ---- stage B: wt[k][o=sm][c] -> Bl ----
    {
      const uint4v* wk = (const uint4v*)((const char*)wt
                          + ((size_t)k * OO + sm) * (CC * 2) + cb * 32);
      uint4v wb0 = wk[0];
      uint4v wb1 = wk[1];
      *(uint4v*)&Bl[sm * 128 + (((cb * 2 + 0) ^ fs) << 4)] = wb0;
      *(uint4v*)&Bl[sm * 128 + (((cb * 2 + 1) ^ fs) << 4)] = wb1;
    }
    // ---- stage A: bilinear sample 16 channels for pixel sm, packed f16 ----
    {
      int pb = (k * 64 + sm) * 4;
      int i0 = ((int)pidx[pb + 0]) << 7;
      int i1 = ((int)pidx[pb + 1]) << 7;
      int i2 = ((int)pidx[pb + 2]) << 7;
      int i3 = ((int)pidx[pb + 3]) << 7;
      float w0 = pwt[pb + 0], w1 = pwt[pb + 1], w2 = pwt[pb + 2], w3 = pwt[pb + 3];
      f16 h0 = (f16)w0, h1 = (f16)w1, h2 = (f16)w2, h3 = (f16)w3;
      f16x2 p0 = {h0, h0}, p1 = {h1, h1}, p2 = {h2, h2}, p3 = {h3, h3};
      int co = cb * 32;
      uint4v c0a = *(const uint4v*)(xb + i0 + co);
      uint4v c0b = *(const uint4v*)(xb + i0 + co + 16);
      uint4v c1a = *(const uint4v*)(xb + i1 + co);
      uint4v c1b = *(const uint4v*)(xb + i1 + co + 16);
      uint4v c2a = *(const uint4v*)(xb + i2 + co);
      uint4v c2b = *(const uint4v*)(xb + i2 + co + 16);
      uint4v c3a = *(const uint4v*)(xb + i3 + co);
      uint4v c3b = *(const uint4v*)(xb + i3 + co + 16);
      uint4v pa, pb2;
      #pragma unroll
      for (int q = 0; q < 4; ++q) {
        f16x2 s  = p0 * bch(c0a[q]) + p1 * bch(c1a[q])
                 + p2 * bch(c2a[q]) + p3 * bch(c3a[q]);
        pa[q] = bcu(s);
        f16x2 s2 = p0 * bch(c0b[q]) + p1 * bch(c1b[q])
                 + p2 * bch(c2b[q]) + p3 * bch(c3b[q]);
        pb2[q] = bcu(s2);
      }
      *(uint4v*)&Al[sm * 128 + (((cb * 2 + 0) ^ fs) << 4)] = pa;
      *(uint4v*)&Al[sm * 128 + (((cb * 2 + 1) ^ fs) << 4)] = pb2;
    }
    __syncthreads();

    // ---- dot2 contraction over this tap's 64 channels ----
    #pragma unroll
    for (int g = 0; g < 8; ++g) {
      uint4v av[4], bv[4];
      #pragma unroll
      for (int p = 0; p < 4; ++p) {
        int row = mg * 4 + p;
        av[p] = *(const uint4v*)&Al[row * 128 + (swz(row, g) << 4)];
      }
      #pragma unroll
      for (int q = 0; q < 4; ++q) {
        int row = og * 4 + q;
        bv[q] = *(const uint4v*)&Bl[row * 128 + (swz(row, g) << 4)];
      }
      #pragma unroll
      for (int p = 0; p < 4; ++p)
        #pragma unroll
        for (int q = 0; q < 4; ++q) {
          float a = acc[p][q];
          a = dot2u(av[p][0], bv[q][0], a);
          a = dot2u(av[p][1], bv[q][1], a);
          a = dot2u(av[p][2], bv[q][2], a);
          a = dot2u(av[p][3], bv[q][3], a);
          acc[p][q] = a;
        }
    }
    __syncthreads();
  }

  // ---- epilogue (verified R3 pattern): out[b][o][hw0 + m] ----
  float* ob = out + (size_t)b * OO * HW;
  #pragma unroll
  for (int q = 0; q < 4; ++q) {
    f32x4 v;
    v[0] = acc[0][q]; v[1] = acc[1][q]; v[2] = acc[2][q]; v[3] = acc[3][q];
    *(f32x4*)(ob + (size_t)(og * 4 + q) * HW + hw0 + mg * 4) = v;
  }
}

extern "C" void kernel_launch(void* const* d_in, const int* in_sizes, int n_in,
                              void* d_out, int out_size, void* d_ws, size_t ws_size,
                              hipStream_t stream) {
  const float* x     = (const float*)d_in[0];
  const float* w_off = (const float*)d_in[1];
  const float* b_off = (const float*)d_in[2];
  const float* w_dcn = (const float*)d_in[3];
  float* out = (float*)d_out;

  // workspace layout (same footprint as verified R3: 14,819,328 B)
  char* ws = (char*)d_ws;
  float* offset = (float*)ws;                                      // 5,308,416 B
  unsigned short* xtp = (unsigned short*)(ws + 5308416);           // 9,437,184 B
  unsigned short* wtp = (unsigned short*)(ws + 5308416 + 9437184); //    73,728 B

  transpose_kernel<<<NPIX / 256, 256, 0, stream>>>(x, xtp);
  wprep_kernel<<<(K2 * OO * CC) / 256, 256, 0, stream>>>(w_dcn, wtp);
  offconv_kernel<<<NPIX / 64, 256, 0, stream>>>(xtp, w_off, b_off, offset);
  dcn_kernel<<<BB * NTILE, 256, 0, stream>>>(xtp, offset, wtp, out);
}

// Round 5
// 113.909 us; speedup vs baseline: 6.5482x; 1.0636x over previous
//
#include <hip/hip_runtime.h>

#define BB 8
#define CC 64
#define HH 96
#define WW 96
#define OO 64
#define KK 3
#define K2 9
#define HW (HH*WW)      // 9216
#define NOFF 18
#define NPIX (BB*HW)    // 73728
#define MT 64           // pixels per dcn block
#define NTILE (HW/MT)   // 144 tiles per image

typedef _Float16 f16;
typedef __attribute__((ext_vector_type(2))) _Float16 f16x2;
typedef __attribute__((ext_vector_type(4))) float f32x4;
typedef __attribute__((ext_vector_type(4))) unsigned int uint4v;

#if __has_builtin(__builtin_amdgcn_fdot2)
__device__ __forceinline__ float dot2u(unsigned a, unsigned b, float c) {
  return __builtin_amdgcn_fdot2(__builtin_bit_cast(f16x2, a),
                                __builtin_bit_cast(f16x2, b), c, false);
}
#else
__device__ __forceinline__ float dot2u(unsigned a, unsigned b, float c) {
  f16x2 ha = __builtin_bit_cast(f16x2, a), hb = __builtin_bit_cast(f16x2, b);
  return c + (float)ha[0] * (float)hb[0] + (float)ha[1] * (float)hb[1];
}
#endif

__device__ __forceinline__ f16x2 bch(unsigned u) { return __builtin_bit_cast(f16x2, u); }
__device__ __forceinline__ unsigned bcu(f16x2 h) { return __builtin_bit_cast(unsigned, h); }

// LDS slot swizzle (row stride 128 B = 8 slots of 16 B) — verified R4
__device__ __forceinline__ int swz(int row, int g) {
  return g ^ (((row >> 2) ^ ((row & 3) << 1)) & 7);
}

// ---------------- Kernel T: NCHW fp32 -> NHWC f16 (1152 blocks) -------------
__global__ __launch_bounds__(256) void transpose_kernel(
    const float* __restrict__ x, unsigned short* __restrict__ xt) {
  int t = threadIdx.x;
  int px = blockIdx.x * 64 + (t & 63);
  int cg = t >> 6;                      // 0..3 -> channels cg*16..+15
  int b = px / HW, hw = px % HW;
  const float* xp = x + (size_t)b * CC * HW + (size_t)(cg * 16) * HW + hw;
  f16 r[16];
  #pragma unroll
  for (int i = 0; i < 16; ++i) r[i] = (f16)xp[i * HW];   // coalesced across lanes
  uint4v v0, v1;
  #pragma unroll
  for (int q = 0; q < 4; ++q) {
    f16x2 a = {r[q*2], r[q*2+1]};       v0[q] = bcu(a);
    f16x2 bq = {r[8+q*2], r[8+q*2+1]};  v1[q] = bcu(bq);
  }
  uint4v* dst = (uint4v*)(xt + (size_t)px * CC + cg * 16);
  dst[0] = v0; dst[1] = v1;
}

// ---------------- Kernel W: w_dcn [O][C][K2] fp32 -> wt [K2][O][C] f16 ------
__global__ void wprep_kernel(const float* __restrict__ w_dcn,
                             unsigned short* __restrict__ wt) {
  int idx = blockIdx.x * 256 + threadIdx.x;   // 36864
  int k = idx / (OO * CC);
  int o = (idx / CC) % OO;
  int c = idx % CC;
  f16 h = (f16)w_dcn[(o * CC + c) * K2 + k];
  wt[idx] = __builtin_bit_cast(unsigned short, h);
}

// ---------------- Kernel O: offset conv via dot2, 2-deep pipeline -----------
#define JW 72   // padded j-row stride in f16
#define DOT4(xv, wv, a) do { a = dot2u((xv)[0],(wv)[0],a); a = dot2u((xv)[1],(wv)[1],a); \
                             a = dot2u((xv)[2],(wv)[2],a); a = dot2u((xv)[3],(wv)[3],a); } while(0)
#define DECLSET(R) uint4v R##0,R##1,R##2,R##3,R##4,R##5,R##6,R##7; bool vld##R = false;
#define LOADT(kt_, R) do { int ky=(kt_)/3, kx=(kt_)%3; int y=h-1+ky, xx=w-1+kx; \
  vld##R = ((unsigned)y<HH)&&((unsigned)xx<WW); \
  int yc=min(max(y,0),HH-1), xc=min(max(xx,0),WW-1); \
  const uint4v* xr_ = xtb + (size_t)(yc*WW+xc)*8; \
  R##0=xr_[0];R##1=xr_[1];R##2=xr_[2];R##3=xr_[3];R##4=xr_[4];R##5=xr_[5];R##6=xr_[6];R##7=xr_[7]; } while(0)
#define USET(kt_, R) do { if (vld##R) { \
  _Pragma("unroll") \
  for (int ji = 0; ji < 5; ++ji) { int j = jg + ji*4; \
    const uint4v* wr_ = (const uint4v*)&wl[((kt_)*NOFF + j)*JW]; \
    float a = acc[ji]; \
    DOT4(R##0,wr_[0],a); DOT4(R##1,wr_[1],a); DOT4(R##2,wr_[2],a); DOT4(R##3,wr_[3],a); \
    DOT4(R##4,wr_[4],a); DOT4(R##5,wr_[5],a); DOT4(R##6,wr_[6],a); DOT4(R##7,wr_[7],a); \
    if (j < NOFF) acc[ji] = a; } } } while(0)

__global__ __launch_bounds__(256) void offconv_kernel(
    const unsigned short* __restrict__ xt, const float* __restrict__ w_off,
    const float* __restrict__ b_off, float* __restrict__ offset) {
  __shared__ unsigned short wl[K2 * NOFF * JW + 2 * JW];   // +pad for gated OOB j reads
  int t = threadIdx.x;
  for (int i = t; i < K2 * NOFF * CC; i += 256) {
    int kt = i / (NOFF * CC);
    int r = i - kt * (NOFF * CC);
    int j = r >> 6, c = r & 63;
    f16 h = (f16)w_off[(j * CC + c) * K2 + kt];
    wl[(kt * NOFF + j) * JW + c] = __builtin_bit_cast(unsigned short, h);
  }
  __syncthreads();

  int px = blockIdx.x * 64 + (t >> 2);
  int jg = t & 3;
  int b = px / HW, hw = px % HW;
  int h = hw / WW, w = hw % WW;

  float acc[5];
  #pragma unroll
  for (int ji = 0; ji < 5; ++ji) {
    int j = jg + ji * 4;
    acc[ji] = (j < NOFF) ? b_off[j] : 0.f;
  }

  const uint4v* xtb = (const uint4v*)(xt + (size_t)b * HW * CC);
  DECLSET(A); DECLSET(B);
  LOADT(0, A);
  LOADT(1, B);
  #pragma unroll
  for (int kt = 0; kt < 7; kt += 2) {
    USET(kt, A);     LOADT(kt + 2, A);
    USET(kt + 1, B); if (kt + 3 < K2) LOADT(kt + 3, B);
  }
  USET(8, A);

  float* op = offset + (size_t)b * NOFF * HW + hw;
  #pragma unroll
  for (int ji = 0; ji < 5; ++ji) {
    int j = jg + ji * 4;
    if (j < NOFF) op[j * HW] = acc[ji];
  }
}

// ---------------- Kernel D: deformable conv, issue-early pipeline -----------
__global__ __launch_bounds__(256) void dcn_kernel(
    const unsigned short* __restrict__ xt,   // [B][HW][C] f16
    const float* __restrict__ offset,        // [B][18][HW] fp32
    const unsigned short* __restrict__ wt,   // [K2][O][C] f16
    float* __restrict__ out) {
  __shared__ unsigned short pidx[576 * 4];
  __shared__ __align__(16) float pwt[576 * 4];
  __shared__ char Al[64 * 128];
  __shared__ char Bl[64 * 128];

  int t = threadIdx.x;
  int blk = blockIdx.x;
  int b = blk / NTILE;
  int hw0 = (blk % NTILE) * MT;

  const char*  xb   = (const char*)(xt + (size_t)b * HW * CC);
  const float* offb = offset + (size_t)b * NOFF * HW + hw0;

  // ---- phase 0: bilinear params (verified R3/R4) ----
  for (int p = t; p < 576; p += 256) {
    int k = p >> 6, m = p & 63;
    int hw = hw0 + m;
    int h = hw / WW, w = hw % WW;
    int ky = k / KK, kx = k % KK;
    float py = offb[(2 * k) * HW + m]     + (float)(h - 1 + ky);
    float px = offb[(2 * k + 1) * HW + m] + (float)(w - 1 + kx);
    float y0f = floorf(py), x0f = floorf(px);
    float wy = py - y0f, wx = px - x0f;
    int y0 = (int)y0f, x0 = (int)x0f;
    int y1 = y0 + 1, x1 = x0 + 1;
    bool vy0 = (unsigned)y0 < HH, vy1 = (unsigned)y1 < HH;
    bool vx0 = (unsigned)x0 < WW, vx1 = (unsigned)x1 < WW;
    int cy0 = min(max(y0, 0), HH - 1), cy1 = min(max(y1, 0), HH - 1);
    int cx0 = min(max(x0, 0), WW - 1), cx1 = min(max(x1, 0), WW - 1);
    pwt[p * 4 + 0] = (1.f - wy) * (1.f - wx) * ((vy0 && vx0) ? 1.f : 0.f);
    pwt[p * 4 + 1] = (1.f - wy) * wx         * ((vy0 && vx1) ? 1.f : 0.f);
    pwt[p * 4 + 2] = wy * (1.f - wx)         * ((vy1 && vx0) ? 1.f : 0.f);
    pwt[p * 4 + 3] = wy * wx                 * ((vy1 && vx1) ? 1.f : 0.f);
    pidx[p * 4 + 0] = (unsigned short)(cy0 * WW + cx0);
    pidx[p * 4 + 1] = (unsigned short)(cy0 * WW + cx1);
    pidx[p * 4 + 2] = (unsigned short)(cy1 * WW + cx0);
    pidx[p * 4 + 3] = (unsigned short)(cy1 * WW + cx1);
  }
  __syncthreads();

  int sm = (t & 15) + (t >> 6) * 16;
  int cb = (t >> 4) & 3;
  int fs = ((sm >> 2) ^ ((sm & 3) << 1)) & 7;
  int mg = t >> 4;
  int og = t & 15;

  float acc[4][4];
  #pragma unroll
  for (int p = 0; p < 4; ++p)
    #pragma unroll
    for (int q = 0; q < 4; ++q) acc[p][q] = 0.f;

  // pipeline registers
  uint4v c0a, c0b, c1a, c1b, c2a, c2b, c3a, c3b, wv0, wv1;
  f32x4 wq;

  auto ISSUE = [&](int k) {
    int pb = (k * 64 + sm) * 4;
    int i0 = ((int)pidx[pb + 0]) << 7;
    int i1 = ((int)pidx[pb + 1]) << 7;
    int i2 = ((int)pidx[pb + 2]) << 7;
    int i3 = ((int)pidx[pb + 3]) << 7;
    wq = *(const f32x4*)&pwt[pb];
    int co = cb * 32;
    c0a = *(const uint4v*)(xb + i0 + co); c0b = *(const uint4v*)(xb + i0 + co + 16);
    c1a = *(const uint4v*)(xb + i1 + co); c1b = *(const uint4v*)(xb + i1 + co + 16);
    c2a = *(const uint4v*)(xb + i2 + co); c2b = *(const uint4v*)(xb + i2 + co + 16);
    c3a = *(const uint4v*)(xb + i3 + co); c3b = *(const uint4v*)(xb + i3 + co + 16);
    const uint4v* wk = (const uint4v*)((const char*)wt
                        + ((size_t)k * OO + sm) * (CC * 2) + cb * 32);
    wv0 = wk[0]; wv1 = wk[1];
  };

  ISSUE(0);
  for (int k = 0; k < K2; ++k) {
    // ---- STAGE: consume pipeline regs -> LDS tile k ----
    *(uint4v*)&Bl[sm * 128 + (((cb * 2 + 0) ^ fs) << 4)] = wv0;
    *(uint4v*)&Bl[sm * 128 + (((cb * 2 + 1) ^ fs) << 4)] = wv1;
    {
      f16 h0 = (f16)wq[0], h1 = (f16)wq[1], h2 = (f16)wq[2], h3 = (f16)wq[3];
      f16x2 p0 = {h0, h0}, p1 = {h1, h1}, p2 = {h2, h2}, p3 = {h3, h3};
      uint4v pa, pb2;
      #pragma unroll
      for (int q = 0; q < 4; ++q) {
        f16x2 s  = p0 * bch(c0a[q]) + p1 * bch(c1a[q])
                 + p2 * bch(c2a[q]) + p3 * bch(c3a[q]);
        pa[q] = bcu(s);
        f16x2 s2 = p0 * bch(c0b[q]) + p1 * bch(c1b[q])
                 + p2 * bch(c2b[q]) + p3 * bch(c3b[q]);
        pb2[q] = bcu(s2);
      }
      *(uint4v*)&Al[sm * 128 + (((cb * 2 + 0) ^ fs) << 4)] = pa;
      *(uint4v*)&Al[sm * 128 + (((cb * 2 + 1) ^ fs) << 4)] = pb2;
    }
    __syncthreads();

    // ---- ISSUE next tap's loads (fly during compute) ----
    if (k < K2 - 1) ISSUE(k + 1);

    // ---- COMPUTE: dot2 contraction (verified R4) ----
    #pragma unroll
    for (int g = 0; g < 8; ++g) {
      uint4v av[4], bv[4];
      #pragma unroll
      for (int p = 0; p < 4; ++p) {
        int row = mg * 4 + p;
        av[p] = *(const uint4v*)&Al[row * 128 + (swz(row, g) << 4)];
      }
      #pragma unroll
      for (int q = 0; q < 4; ++q) {
        int row = og * 4 + q;
        bv[q] = *(const uint4v*)&Bl[row * 128 + (swz(row, g) << 4)];
      }
      #pragma unroll
      for (int p = 0; p < 4; ++p)
        #pragma unroll
        for (int q = 0; q < 4; ++q) {
          float a = acc[p][q];
          a = dot2u(av[p][0], bv[q][0], a);
          a = dot2u(av[p][1], bv[q][1], a);
          a = dot2u(av[p][2], bv[q][2], a);
          a = dot2u(av[p][3], bv[q][3], a);
          acc[p][q] = a;
        }
    }
    __syncthreads();
  }

  // ---- epilogue (verified R3/R4) ----
  float* ob = out + (size_t)b * OO * HW;
  #pragma unroll
  for (int q = 0; q < 4; ++q) {
    f32x4 v;
    v[0] = acc[0][q]; v[1] = acc[1][q]; v[2] = acc[2][q]; v[3] = acc[3][q];
    *(f32x4*)(ob + (size_t)(og * 4 + q) * HW + hw0 + mg * 4) = v;
  }
}

extern "C" void kernel_launch(void* const* d_in, const int* in_sizes, int n_in,
                              void* d_out, int out_size, void* d_ws, size_t ws_size,
                              hipStream_t stream) {
  const float* x     = (const float*)d_in[0];
  const float* w_off = (const float*)d_in[1];
  const float* b_off = (const float*)d_in[2];
  const float* w_dcn = (const float*)d_in[3];
  float* out = (float*)d_out;

  char* ws = (char*)d_ws;
  float* offset = (float*)ws;                                      // 5,308,416 B
  unsigned short* xtp = (unsigned short*)(ws + 5308416);           // 9,437,184 B
  unsigned short* wtp = (unsigned short*)(ws + 5308416 + 9437184); //    73,728 B

  transpose_kernel<<<NPIX / 64, 256, 0, stream>>>(x, xtp);
  wprep_kernel<<<(K2 * OO * CC) / 256, 256, 0, stream>>>(w_dcn, wtp);
  offconv_kernel<<<NPIX / 64, 256, 0, stream>>>(xtp, w_off, b_off, offset);
  dcn_kernel<<<BB * NTILE, 256, 0, stream>>>(xtp, offset, wtp, out);
}